// Round 5
// baseline (1510.987 us; speedup 1.0000x reference)
//
#include <hip/hip_runtime.h>
#include <stdint.h>

typedef unsigned short u16;
typedef unsigned int   u32;
typedef float f32x4  __attribute__((ext_vector_type(4)));
typedef _Float16 f16x4 __attribute__((ext_vector_type(4)));
typedef _Float16 f16x8 __attribute__((ext_vector_type(8)));

#define NN0 200000
#define NN1 100000
#define NN2 50000
#define EE0 1600000
#define EE1 800000
#define DD  256
#define CC  7
#define KK  40

// fp16 2-level split-weight image geometry:
// per (layer, ntile, chunk): 2 levels x 128 rows x 32 fp16 = 16384 B, XOR-swizzled
// swizzle: 16-B quad q (k>>3) stored at q ^ ((row>>1)&3)  -> conflict-free b128 r/w
#define LVL2_U16 4096           // u16 per level (128 rows x 32)
#define IMG_U16  8192           // u16 per chunk image (2 levels)

// ---------------- split f32 -> 2 fp16 (residual) ----------------
static __device__ __forceinline__ void split2(float x, _Float16& t0, _Float16& t1) {
    t0 = (_Float16)x;
    t1 = (_Float16)(x - (float)t0);
}

static __device__ __forceinline__ f16x8 pack8(const _Float16* h) {
    f16x8 v;
#pragma unroll
    for (int i = 0; i < 8; ++i) v[i] = h[i];
    return v;
}

static __device__ __forceinline__ void async16(const void* g, void* l) {
    __builtin_amdgcn_global_load_lds(
        (const __attribute__((address_space(1))) void*)g,
        (__attribute__((address_space(3))) void*)l, 16, 0, 0);
}

// ---------------- histogram ----------------
__global__ void hist_kernel(const int* __restrict__ dst, int* __restrict__ cnt, int n) {
    int i = blockIdx.x * blockDim.x + threadIdx.x;
    if (i < n) atomicAdd(&cnt[dst[i]], 1);
}

// ---------------- scan (1024 elems/block) ----------------
__global__ void scan_block_kernel(const int* __restrict__ in, int* __restrict__ out,
                                  int* __restrict__ partials, int n) {
    __shared__ int sd[256];
    int t = threadIdx.x;
    int base = blockIdx.x * 1024 + t * 4;
    int v0 = (base + 0 < n) ? in[base + 0] : 0;
    int v1 = (base + 1 < n) ? in[base + 1] : 0;
    int v2 = (base + 2 < n) ? in[base + 2] : 0;
    int v3 = (base + 3 < n) ? in[base + 3] : 0;
    int p0 = v0, p1 = p0 + v1, p2 = p1 + v2, p3 = p2 + v3;
    sd[t] = p3;
    __syncthreads();
    for (int off = 1; off < 256; off <<= 1) {
        int x = (t >= off) ? sd[t - off] : 0;
        __syncthreads();
        sd[t] += x;
        __syncthreads();
    }
    int excl = sd[t] - p3;
    if (base + 0 < n) out[base + 0] = excl + p0;
    if (base + 1 < n) out[base + 1] = excl + p1;
    if (base + 2 < n) out[base + 2] = excl + p2;
    if (base + 3 < n) out[base + 3] = excl + p3;
    if (t == 255) partials[blockIdx.x] = sd[255];
}

__global__ void scan_partials_kernel(int* __restrict__ partials, int nb) {
    __shared__ int sd[256];
    int t = threadIdx.x;
    int v = (t < nb) ? partials[t] : 0;
    sd[t] = v;
    __syncthreads();
    for (int off = 1; off < 256; off <<= 1) {
        int x = (t >= off) ? sd[t - off] : 0;
        __syncthreads();
        sd[t] += x;
        __syncthreads();
    }
    if (t < nb) partials[t] = sd[t];
}

__global__ void scan_add_kernel(int* __restrict__ out, const int* __restrict__ partials, int n) {
    int b = blockIdx.x;
    if (b == 0) return;
    int add = partials[b - 1];
    int base = b * 1024 + threadIdx.x * 4;
    if (base + 0 < n) out[base + 0] += add;
    if (base + 1 < n) out[base + 1] += add;
    if (base + 2 < n) out[base + 2] += add;
    if (base + 3 < n) out[base + 3] += add;
}

// ---------------- CSR fill ----------------
__global__ void fill_kernel(const int* __restrict__ esrc, const int* __restrict__ edst,
                            const int* __restrict__ rp, int* __restrict__ cur,
                            int* __restrict__ ss, int n) {
    int i = blockIdx.x * blockDim.x + threadIdx.x;
    if (i < n) {
        int d = edst[i];
        int p = rp[d] + atomicAdd(&cur[d], 1);
        ss[p] = esrc[i];
    }
}

// ---------------- f32 -> fp16 streaming convert (8 elems/thread) ----------------
__global__ void to_fp16(const float* __restrict__ in, _Float16* __restrict__ outp, long n) {
    long i = ((long)blockIdx.x * blockDim.x + threadIdx.x) * 8;
    if (i >= n) return;
    f32x4 a = *reinterpret_cast<const f32x4*>(in + i);
    f32x4 b = *reinterpret_cast<const f32x4*>(in + i + 4);
    f16x8 h;
    h[0] = (_Float16)a[0]; h[1] = (_Float16)a[1]; h[2] = (_Float16)a[2]; h[3] = (_Float16)a[3];
    h[4] = (_Float16)b[0]; h[5] = (_Float16)b[1]; h[6] = (_Float16)b[2]; h[7] = (_Float16)b[3];
    *reinterpret_cast<f16x8*>(outp + i) = h;
}

// ---------------- gather + mean (one wave per dst node), fp16 source ----------------
// fp16 rows (512 B): halves the structural ~3.9x XCD-amplified miss volume of the
// random gather (round-1 finding). Accumulate f32.
__global__ void gather_mean_fp16(const _Float16* __restrict__ Xh, const int* __restrict__ rp,
                                 const int* __restrict__ ss, float* __restrict__ mean, int ndst) {
    int wave = threadIdx.x >> 6, lane = threadIdx.x & 63;
    int d = blockIdx.x * 4 + wave;
    if (d >= ndst) return;
    int beg = rp[d], end = rp[d + 1];
    int lo4 = lane * 4;
    f32x4 a0 = (f32x4)(0.f), a1 = (f32x4)(0.f), a2 = (f32x4)(0.f), a3 = (f32x4)(0.f);
    int j = beg;
    for (; j + 8 <= end; j += 8) {
        int s0 = ss[j + 0], s1 = ss[j + 1], s2 = ss[j + 2], s3 = ss[j + 3];
        int s4 = ss[j + 4], s5 = ss[j + 5], s6 = ss[j + 6], s7 = ss[j + 7];
        f16x4 h0 = *reinterpret_cast<const f16x4*>(Xh + (size_t)s0 * DD + lo4);
        f16x4 h1 = *reinterpret_cast<const f16x4*>(Xh + (size_t)s1 * DD + lo4);
        f16x4 h2 = *reinterpret_cast<const f16x4*>(Xh + (size_t)s2 * DD + lo4);
        f16x4 h3 = *reinterpret_cast<const f16x4*>(Xh + (size_t)s3 * DD + lo4);
        f16x4 h4 = *reinterpret_cast<const f16x4*>(Xh + (size_t)s4 * DD + lo4);
        f16x4 h5 = *reinterpret_cast<const f16x4*>(Xh + (size_t)s5 * DD + lo4);
        f16x4 h6 = *reinterpret_cast<const f16x4*>(Xh + (size_t)s6 * DD + lo4);
        f16x4 h7 = *reinterpret_cast<const f16x4*>(Xh + (size_t)s7 * DD + lo4);
        a0 += __builtin_convertvector(h0, f32x4);
        a1 += __builtin_convertvector(h1, f32x4);
        a2 += __builtin_convertvector(h2, f32x4);
        a3 += __builtin_convertvector(h3, f32x4);
        a0 += __builtin_convertvector(h4, f32x4);
        a1 += __builtin_convertvector(h5, f32x4);
        a2 += __builtin_convertvector(h6, f32x4);
        a3 += __builtin_convertvector(h7, f32x4);
    }
    for (; j + 4 <= end; j += 4) {
        int s0 = ss[j + 0], s1 = ss[j + 1], s2 = ss[j + 2], s3 = ss[j + 3];
        f16x4 h0 = *reinterpret_cast<const f16x4*>(Xh + (size_t)s0 * DD + lo4);
        f16x4 h1 = *reinterpret_cast<const f16x4*>(Xh + (size_t)s1 * DD + lo4);
        f16x4 h2 = *reinterpret_cast<const f16x4*>(Xh + (size_t)s2 * DD + lo4);
        f16x4 h3 = *reinterpret_cast<const f16x4*>(Xh + (size_t)s3 * DD + lo4);
        a0 += __builtin_convertvector(h0, f32x4);
        a1 += __builtin_convertvector(h1, f32x4);
        a2 += __builtin_convertvector(h2, f32x4);
        a3 += __builtin_convertvector(h3, f32x4);
    }
    for (; j < end; ++j) {
        int s = ss[j];
        f16x4 h0 = *reinterpret_cast<const f16x4*>(Xh + (size_t)s * DD + lo4);
        a0 += __builtin_convertvector(h0, f32x4);
    }
    f32x4 s = (a0 + a1) + (a2 + a3);
    int dg = end - beg;
    float inv = 1.0f / (float)(dg > 0 ? dg : 1);
    s *= inv;
    *reinterpret_cast<f32x4*>(mean + (size_t)d * DD + lo4) = s;
}

// ---------------- build 2-level fp16 split weight image (pre-swizzled global) ----------------
// img[blk = layer*32 + ntile*16 + chunk][level 2][row 128][32 fp16], quad-XOR-swizzled.
// row = output col n (within ntile), k = chunk*32 + (0..31); W row-major [n][k&255]
__global__ void build_wimg(const float* __restrict__ Wa0, const float* __restrict__ Wb0,
                           const float* __restrict__ Wa1, const float* __restrict__ Wb1,
                           u16* __restrict__ img) {
    int blk = blockIdx.x;           // 0..63
    int layer = blk >> 5;
    int ntile = (blk >> 4) & 1;
    int chunk = blk & 15;
    const float* Wa = layer ? Wa1 : Wa0;
    const float* Wb = layer ? Wb1 : Wb0;
    int t = threadIdx.x;
    int row = t >> 1, half = t & 1;
    int n = ntile * 128 + row;
    int kg = chunk * 32 + half * 16;
    const float* W = (kg < 256) ? Wa : Wb;
    int kk = kg & 255;
    const float* src = W + (size_t)n * 256 + kk;
    float x[16];
#pragma unroll
    for (int j = 0; j < 16; j += 4) {
        float4 v = *reinterpret_cast<const float4*>(src + j);
        x[j] = v.x; x[j + 1] = v.y; x[j + 2] = v.z; x[j + 3] = v.w;
    }
    _Float16 h0[16], h1[16];
#pragma unroll
    for (int j = 0; j < 16; ++j) split2(x[j], h0[j], h1[j]);
    int rs = (row >> 1) & 3;
    int q0 = (half * 2 + 0) ^ rs;
    int q1 = (half * 2 + 1) ^ rs;
    u16* base = img + (size_t)blk * IMG_U16 + row * 32;
    *reinterpret_cast<f16x8*>(base + q0 * 8)            = pack8(h0);
    *reinterpret_cast<f16x8*>(base + q1 * 8)            = pack8(h0 + 8);
    *reinterpret_cast<f16x8*>(base + LVL2_U16 + q0 * 8) = pack8(h1);
    *reinterpret_cast<f16x8*>(base + LVL2_U16 + q1 * 8) = pack8(h1 + 8);
}

// ---------------- 2-level fp16 split MFMA GEMM: out = relu([X0|X1] @ [Wa|Wb]^T + b) ----------
// A = f32 in global (split2 in-kernel), B = pre-split+pre-swizzled image, out f32 M x 256.
// block: 256 thr (4 waves), tile 128M x 128N; wave: 64x64 = 4x4 subtiles of 16x16x32 f16.
// 3 MFMA per subtile per chunk: t0w0, t0w1, t1w0 (dropped t1w1 ~ 2^-22 relative).
__global__ __launch_bounds__(256, 3) void gemm_f16(const float* __restrict__ X0,
                                                   const float* __restrict__ X1,
                                                   const u16* __restrict__ imgL,
                                                   const float* __restrict__ bias,
                                                   float* __restrict__ out,
                                                   _Float16* __restrict__ outh, int M) {
    __shared__ __align__(16) u16 Asl[2 * LVL2_U16];
    __shared__ __align__(16) u16 Bsl[2 * LVL2_U16];
    int t = threadIdx.x;
    int wave = t >> 6, lane = t & 63;
    int m0 = blockIdx.x * 128;
    int ntile = blockIdx.y;
    int wy = wave >> 1, wx = wave & 1;     // wave position: m-half, n-half

    f32x4 acc[4][4];
#pragma unroll
    for (int i = 0; i < 4; ++i)
#pragma unroll
        for (int j = 0; j < 4; ++j) acc[i][j] = (f32x4)(0.f);

    // A staging mapping: 256 thr -> 128 rows x 2 k-halves (16 f32 each)
    int arow_l = t >> 1;
    int akh = t & 1;
    int arow = m0 + arow_l; if (arow >= M) arow = M - 1;

    // fragment positions: A/B operand elem j -> k = (lane>>4)*8 + j  => quad q = lane>>4
    int fr = lane & 15;
    int q  = lane >> 4;
    int frm = wy * 64 + fr;
    int frn = wx * 64 + fr;

    const u16* imgT = imgL + (size_t)ntile * 16 * IMG_U16;

    for (int c = 0; c < 16; ++c) {
        // ---- stage B: async global->LDS, 16 segs of 1024 B (wave-uniform seg), linear copy
        const char* src = (const char*)(imgT + (size_t)c * IMG_U16);
#pragma unroll
        for (int i = 0; i < 4; ++i) {
            int seg = wave * 4 + i;
            async16(src + seg * 1024 + lane * 16, (char*)Bsl + seg * 1024 + lane * 16);
        }
        // ---- stage A: load 16 f32, split2, write 4 swizzled quads
        {
            const float* Xs = (c < 8) ? X0 : X1;
            int kc = (c & 7) * 32;
            const float* p = Xs + (size_t)arow * 256 + kc + akh * 16;
            float x[16];
#pragma unroll
            for (int j = 0; j < 16; j += 4) {
                float4 v = *reinterpret_cast<const float4*>(p + j);
                x[j] = v.x; x[j + 1] = v.y; x[j + 2] = v.z; x[j + 3] = v.w;
            }
            _Float16 h0[16], h1[16];
#pragma unroll
            for (int j = 0; j < 16; ++j) split2(x[j], h0[j], h1[j]);
            int rs = (arow_l >> 1) & 3;
            int q0 = (akh * 2 + 0) ^ rs;
            int q1 = (akh * 2 + 1) ^ rs;
            u16* d = Asl + arow_l * 32;
            *reinterpret_cast<f16x8*>(d + q0 * 8)            = pack8(h0);
            *reinterpret_cast<f16x8*>(d + q1 * 8)            = pack8(h0 + 8);
            *reinterpret_cast<f16x8*>(d + LVL2_U16 + q0 * 8) = pack8(h1);
            *reinterpret_cast<f16x8*>(d + LVL2_U16 + q1 * 8) = pack8(h1 + 8);
        }
        __syncthreads();
        // ---- fragments + MFMA (3 per subtile)
        f16x8 bf[4][2];
#pragma unroll
        for (int ns = 0; ns < 4; ++ns) {
            int r = frn + ns * 16;
            int off = r * 32 + ((q ^ ((r >> 1) & 3))) * 8;
            bf[ns][0] = *reinterpret_cast<const f16x8*>(Bsl + off);
            bf[ns][1] = *reinterpret_cast<const f16x8*>(Bsl + LVL2_U16 + off);
        }
#pragma unroll
        for (int ms = 0; ms < 4; ++ms) {
            int r = frm + ms * 16;
            int off = r * 32 + ((q ^ ((r >> 1) & 3))) * 8;
            f16x8 af0 = *reinterpret_cast<const f16x8*>(Asl + off);
            f16x8 af1 = *reinterpret_cast<const f16x8*>(Asl + LVL2_U16 + off);
#pragma unroll
            for (int ns = 0; ns < 4; ++ns) {
                f32x4 a = acc[ms][ns];
                a = __builtin_amdgcn_mfma_f32_16x16x32_f16(af0, bf[ns][0], a, 0, 0, 0);
                a = __builtin_amdgcn_mfma_f32_16x16x32_f16(af0, bf[ns][1], a, 0, 0, 0);
                a = __builtin_amdgcn_mfma_f32_16x16x32_f16(af1, bf[ns][0], a, 0, 0, 0);
                acc[ms][ns] = a;
            }
        }
        __syncthreads();
    }
    // ---- epilogue: +bias, relu, store f32 (C/D: col=lane&15, row=(lane>>4)*4+reg)
#pragma unroll
    for (int ms = 0; ms < 4; ++ms) {
        int rbase = m0 + wy * 64 + ms * 16 + (lane >> 4) * 4;
#pragma unroll
        for (int ns = 0; ns < 4; ++ns) {
            int col = ntile * 128 + wx * 64 + ns * 16 + (lane & 15);
            float bcol = bias[col];
#pragma unroll
            for (int r = 0; r < 4; ++r) {
                int row = rbase + r;
                if (row < M) {
                    float v = fmaxf(acc[ms][ns][r] + bcol, 0.f);
                    out[(size_t)row * DD + col] = v;
                    if (outh) outh[(size_t)row * DD + col] = (_Float16)v;
                }
            }
        }
    }
}

// ---------------- head, pass 1: scores -> argmax + class histogram ----------------
// wave = 4 nodes x 16 lanes; lane g covers d = g*32..g*32+31 (f32 reads, same
// inputs as previous passing kernel -> no new argmax-flip risk). 4-deep width-16
// shuffle reduce replaces the old 6-deep width-64 chain.
__global__ void score_kernel(const float* __restrict__ h2, const float* __restrict__ h1,
                             const float* __restrict__ Wp, int* __restrict__ bcout,
                             int* __restrict__ gcnt) {
    __shared__ int lcnt[CC];
    int t = threadIdx.x;
    if (t < CC) lcnt[t] = 0;
    __syncthreads();
    int wave = t >> 6, lane = t & 63;
    int ns = lane >> 4, g = lane & 15;
    int n = (blockIdx.x * 4 + wave) * 4 + ns;   // 3125 blocks * 16 = 50000 exact
    int d0 = g * 32;
    const float* src = (d0 < 256) ? (h2 + (size_t)n * DD + d0)
                                  : (h1 + (size_t)n * DD + (d0 - 256));
    f32x4 x[8];
#pragma unroll
    for (int j = 0; j < 8; ++j) x[j] = *reinterpret_cast<const f32x4*>(src + j * 4);
    float best = -3.0e38f; int bc = 0;
#pragma unroll
    for (int c = 0; c < CC; ++c) {
        const float* w = Wp + (size_t)c * 512 + d0;
        f32x4 a = (f32x4)(0.f);
#pragma unroll
        for (int j = 0; j < 8; ++j)
            a += x[j] * *reinterpret_cast<const f32x4*>(w + j * 4);
        float p = (a[0] + a[1]) + (a[2] + a[3]);
        p += __shfl_xor(p, 1, 16);
        p += __shfl_xor(p, 2, 16);
        p += __shfl_xor(p, 4, 16);
        p += __shfl_xor(p, 8, 16);
        if (p > best) { best = p; bc = c; }  // strict > : first-index tie-break
    }
    if (g == 0) {
        bcout[n] = bc;
        atomicAdd(&lcnt[bc], 1);
    }
    __syncthreads();
    if (t < CC) atomicAdd(&gcnt[t], lcnt[t]);
}

// ---------------- head, pass 1.5: exclusive scan of 7 class counts ----------------
__global__ void scan7_kernel(const int* __restrict__ gcnt, int* __restrict__ cbase,
                             int* __restrict__ cur7) {
    if (threadIdx.x == 0 && blockIdx.x == 0) {
        int s = 0;
        for (int c = 0; c < CC; ++c) { cbase[c] = s; s += gcnt[c]; cur7[c] = 0; }
        cbase[CC] = s;
    }
}

// ---------------- head, pass 1.75: class-bucketed node list (block-aggregated) --------
__global__ void fillc_kernel(const int* __restrict__ bc, const int* __restrict__ cbase,
                             int* __restrict__ cur7, int* __restrict__ nlist) {
    __shared__ int lcnt[CC];
    __shared__ int lbase[CC];
    int t = threadIdx.x;
    int n = blockIdx.x * 256 + t;
    if (t < CC) lcnt[t] = 0;
    __syncthreads();
    int c = 0, myofs = 0;
    bool act = n < NN2;
    if (act) { c = bc[n]; myofs = atomicAdd(&lcnt[c], 1); }
    __syncthreads();
    if (t < CC) lbase[t] = lcnt[t] ? atomicAdd(&cur7[t], lcnt[t]) : 0;
    __syncthreads();
    if (act) nlist[cbase[c] + lbase[c] + myofs] = n;
}

// ---------------- head, pass 2: selected projection over bucketed nodes ----------------
// wave = 4 same-class nodes (bucketed) -> the 4 node-groups issue IDENTICAL weight
// addresses (one L2 request, was 4) ; weight L2 traffic 4.8GB -> ~1.0GB.
__global__ void proj_kernel(const float* __restrict__ h2, const float* __restrict__ h1,
                            const float* __restrict__ Wpp, const int* __restrict__ nlist,
                            const int* __restrict__ bcin, float* __restrict__ out) {
    int t = threadIdx.x;
    int wave = t >> 6, lane = t & 63;
    int ns = lane >> 4, g = lane & 15;
    int i = (blockIdx.x * 4 + wave) * 4 + ns;   // 3125 blocks * 16 = 50000 exact
    int n = nlist[i];
    int c = bcin[n];
    int d0 = g * 32;
    const float* src = (d0 < 256) ? (h2 + (size_t)n * DD + d0)
                                  : (h1 + (size_t)n * DD + (d0 - 256));
    f32x4 x[8];
#pragma unroll
    for (int j = 0; j < 8; ++j) x[j] = *reinterpret_cast<const f32x4*>(src + j * 4);
    const float* wb = Wpp + (size_t)c * KK * 512 + d0;
    for (int k = 0; k < KK; ++k) {
        const float* w = wb + (size_t)k * 512;
        f32x4 a = (f32x4)(0.f);
#pragma unroll
        for (int j = 0; j < 8; ++j)
            a += x[j] * *reinterpret_cast<const f32x4*>(w + j * 4);
        float p = (a[0] + a[1]) + (a[2] + a[3]);
        p += __shfl_xor(p, 1, 16);
        p += __shfl_xor(p, 2, 16);
        p += __shfl_xor(p, 4, 16);
        p += __shfl_xor(p, 8, 16);
        if (g == (k & 15)) out[(size_t)n * KK + k] = p;
    }
}

extern "C" void kernel_launch(void* const* d_in, const int* in_sizes, int n_in,
                              void* d_out, int out_size, void* d_ws, size_t ws_size,
                              hipStream_t stream) {
    const float* inputs  = (const float*)d_in[0];
    const float* Wself0  = (const float*)d_in[1];
    const float* Wneigh0 = (const float*)d_in[2];
    const float* b0      = (const float*)d_in[3];
    const float* Wself1  = (const float*)d_in[4];
    const float* Wneigh1 = (const float*)d_in[5];
    const float* b1      = (const float*)d_in[6];
    const float* Wp      = (const float*)d_in[7];
    const float* Wpp     = (const float*)d_in[8];
    const int* es0 = (const int*)d_in[9];
    const int* ed0 = (const int*)d_in[10];
    const int* es1 = (const int*)d_in[11];
    const int* ed1 = (const int*)d_in[12];

    char* ws = (char*)d_ws;
    size_t off = 0;
    auto alloc = [&](size_t bytes) -> void* {
        void* p = (void*)(ws + off);
        off += (bytes + 255) & ~(size_t)255;
        return p;
    };
    // zero-initialized region (one memset)
    int* cnt0 = (int*)alloc((size_t)NN1 * 4);
    int* cnt1 = (int*)alloc((size_t)NN2 * 4);
    int* cur0 = (int*)alloc((size_t)NN1 * 4);
    int* cur1 = (int*)alloc((size_t)NN2 * 4);
    int* rp0  = (int*)alloc((size_t)(NN1 + 1) * 4);
    int* rp1  = (int*)alloc((size_t)(NN2 + 1) * 4);
    int* part0 = (int*)alloc(1024);
    int* part1 = (int*)alloc(1024);
    int* gcnt  = (int*)alloc(CC * 4);          // class histogram (zeroed)
    size_t zero_bytes = off;
    // uninitialized scratch
    int*   ss0   = (int*)alloc((size_t)EE0 * 4);
    int*   ss1   = (int*)alloc((size_t)EE1 * 4);
    int*   bc    = (int*)alloc((size_t)NN2 * 4);
    int*   nlist = (int*)alloc((size_t)NN2 * 4);
    int*   cbase = (int*)alloc((CC + 1) * 4);
    int*   cur7  = (int*)alloc(CC * 4);        // zeroed by scan7_kernel
    u16*   wimg  = (u16*)alloc((size_t)64 * IMG_U16 * 2);     // 64 chunk-images x 16384 B
    // xh (fp16 inputs, 102.4MB) aliases h1 (f32, 102.4MB): xh is dead before
    // gemm0 writes h1 (serial stream: to_fp16 -> gather0 reads xh -> gemm0 writes h1).
    _Float16* xh = (_Float16*)alloc((size_t)NN0 * DD * 2);
    float*    h1 = (float*)xh;
    _Float16* h1h  = (_Float16*)alloc((size_t)NN1 * DD * 2);  // fp16 shadow of h1 for gather1
    float* mean0 = (float*)alloc((size_t)NN1 * DD * 4);
    float* mean1 = mean0;                      // mean0 dead after gemm0; reuse
    float* h2    = mean0 + (size_t)NN2 * DD;   // second half of the same region

    hipMemsetAsync(d_ws, 0, zero_bytes, stream);

    // CSR build, layer 0 and 1
    hist_kernel<<<(EE0 + 255) / 256, 256, 0, stream>>>(ed0, cnt0, EE0);
    hist_kernel<<<(EE1 + 255) / 256, 256, 0, stream>>>(ed1, cnt1, EE1);
    int nb0 = (NN1 + 1023) / 1024, nb1 = (NN2 + 1023) / 1024;
    scan_block_kernel<<<nb0, 256, 0, stream>>>(cnt0, rp0 + 1, part0, NN1);
    scan_partials_kernel<<<1, 256, 0, stream>>>(part0, nb0);
    scan_add_kernel<<<nb0, 256, 0, stream>>>(rp0 + 1, part0, NN1);
    scan_block_kernel<<<nb1, 256, 0, stream>>>(cnt1, rp1 + 1, part1, NN2);
    scan_partials_kernel<<<1, 256, 0, stream>>>(part1, nb1);
    scan_add_kernel<<<nb1, 256, 0, stream>>>(rp1 + 1, part1, NN2);
    fill_kernel<<<(EE0 + 255) / 256, 256, 0, stream>>>(es0, ed0, rp0, cur0, ss0, EE0);
    fill_kernel<<<(EE1 + 255) / 256, 256, 0, stream>>>(es1, ed1, rp1, cur1, ss1, EE1);

    // split weights into pre-swizzled fp16 images (both layers)
    build_wimg<<<64, 256, 0, stream>>>(Wself0, Wneigh0, Wself1, Wneigh1, wimg);

    // fp16 copy of inputs for the gather (halves random-gather miss bytes)
    long nx = (long)NN0 * DD;
    to_fp16<<<(int)(nx / 8 / 256), 256, 0, stream>>>(inputs, xh, nx);

    // layer 0: mean aggregate (fp16 gather) + split-fp16 MFMA GEMM (relu, + fp16 shadow h1h)
    gather_mean_fp16<<<(NN1 + 3) / 4, 256, 0, stream>>>(xh, rp0, ss0, mean0, NN1);
    dim3 g0((NN1 + 127) / 128, 2);
    gemm_f16<<<g0, 256, 0, stream>>>(inputs, mean0, wimg, b0, h1, h1h, NN1);

    // layer 1 (gather reads fp16 shadow)
    gather_mean_fp16<<<(NN2 + 3) / 4, 256, 0, stream>>>(h1h, rp1, ss1, mean1, NN2);
    dim3 g1((NN2 + 127) / 128, 2);
    gemm_f16<<<g1, 256, 0, stream>>>(h1, mean1, wimg + (size_t)32 * IMG_U16, b1, h2, nullptr, NN2);

    // head: scores+argmax -> class-bucketed node list -> selected projection
    score_kernel<<<NN2 / 16, 256, 0, stream>>>(h2, h1, Wp, bc, gcnt);
    scan7_kernel<<<1, 64, 0, stream>>>(gcnt, cbase, cur7);
    fillc_kernel<<<(NN2 + 255) / 256, 256, 0, stream>>>(bc, cbase, cur7, nlist);
    proj_kernel<<<NN2 / 16, 256, 0, stream>>>(h2, h1, Wpp, nlist, bc, (float*)d_out);
}

// Round 6
// 1042.311 us; speedup vs baseline: 1.4497x; 1.4497x over previous
//
#include <hip/hip_runtime.h>
#include <stdint.h>

typedef unsigned short u16;
typedef unsigned int   u32;
typedef float f32x4  __attribute__((ext_vector_type(4)));
typedef _Float16 f16x4 __attribute__((ext_vector_type(4)));
typedef _Float16 f16x8 __attribute__((ext_vector_type(8)));

#define NN0 200000
#define NN1 100000
#define NN2 50000
#define EE0 1600000
#define EE1 800000
#define DD  256
#define CC  7
#define KK  40
#define NHEAD 288               // 7 scores + 280 proj + 1 pad col

// fp16 2-level split-weight image geometry:
// per (ntile, chunk): 2 levels x 128 rows x 32 fp16 = 16384 B, XOR-swizzled
// swizzle: 16-B quad q (k>>3) stored at q ^ ((row>>1)&3)  -> conflict-free b128 r/w
#define LVL2_U16 4096           // u16 per level (128 rows x 32)
#define IMG_U16  8192           // u16 per chunk image (2 levels)

// ---------------- split f32 -> 2 fp16 (residual) ----------------
static __device__ __forceinline__ void split2(float x, _Float16& t0, _Float16& t1) {
    t0 = (_Float16)x;
    t1 = (_Float16)(x - (float)t0);
}

static __device__ __forceinline__ f16x8 pack8(const _Float16* h) {
    f16x8 v;
#pragma unroll
    for (int i = 0; i < 8; ++i) v[i] = h[i];
    return v;
}

static __device__ __forceinline__ void async16(const void* g, void* l) {
    __builtin_amdgcn_global_load_lds(
        (const __attribute__((address_space(1))) void*)g,
        (__attribute__((address_space(3))) void*)l, 16, 0, 0);
}

// ---------------- histogram ----------------
__global__ void hist_kernel(const int* __restrict__ dst, int* __restrict__ cnt, int n) {
    int i = blockIdx.x * blockDim.x + threadIdx.x;
    if (i < n) atomicAdd(&cnt[dst[i]], 1);
}

// ---------------- scan (1024 elems/block) ----------------
__global__ void scan_block_kernel(const int* __restrict__ in, int* __restrict__ out,
                                  int* __restrict__ partials, int n) {
    __shared__ int sd[256];
    int t = threadIdx.x;
    int base = blockIdx.x * 1024 + t * 4;
    int v0 = (base + 0 < n) ? in[base + 0] : 0;
    int v1 = (base + 1 < n) ? in[base + 1] : 0;
    int v2 = (base + 2 < n) ? in[base + 2] : 0;
    int v3 = (base + 3 < n) ? in[base + 3] : 0;
    int p0 = v0, p1 = p0 + v1, p2 = p1 + v2, p3 = p2 + v3;
    sd[t] = p3;
    __syncthreads();
    for (int off = 1; off < 256; off <<= 1) {
        int x = (t >= off) ? sd[t - off] : 0;
        __syncthreads();
        sd[t] += x;
        __syncthreads();
    }
    int excl = sd[t] - p3;
    if (base + 0 < n) out[base + 0] = excl + p0;
    if (base + 1 < n) out[base + 1] = excl + p1;
    if (base + 2 < n) out[base + 2] = excl + p2;
    if (base + 3 < n) out[base + 3] = excl + p3;
    if (t == 255) partials[blockIdx.x] = sd[255];
}

__global__ void scan_partials_kernel(int* __restrict__ partials, int nb) {
    __shared__ int sd[256];
    int t = threadIdx.x;
    int v = (t < nb) ? partials[t] : 0;
    sd[t] = v;
    __syncthreads();
    for (int off = 1; off < 256; off <<= 1) {
        int x = (t >= off) ? sd[t - off] : 0;
        __syncthreads();
        sd[t] += x;
        __syncthreads();
    }
    if (t < nb) partials[t] = sd[t];
}

__global__ void scan_add_kernel(int* __restrict__ out, const int* __restrict__ partials, int n) {
    int b = blockIdx.x;
    if (b == 0) return;
    int add = partials[b - 1];
    int base = b * 1024 + threadIdx.x * 4;
    if (base + 0 < n) out[base + 0] += add;
    if (base + 1 < n) out[base + 1] += add;
    if (base + 2 < n) out[base + 2] += add;
    if (base + 3 < n) out[base + 3] += add;
}

// ---------------- CSR fill ----------------
__global__ void fill_kernel(const int* __restrict__ esrc, const int* __restrict__ edst,
                            const int* __restrict__ rp, int* __restrict__ cur,
                            int* __restrict__ ss, int n) {
    int i = blockIdx.x * blockDim.x + threadIdx.x;
    if (i < n) {
        int d = edst[i];
        int p = rp[d] + atomicAdd(&cur[d], 1);
        ss[p] = esrc[i];
    }
}

// ---------------- f32 -> fp16 streaming convert (8 elems/thread) ----------------
__global__ void to_fp16(const float* __restrict__ in, _Float16* __restrict__ outp, long n) {
    long i = ((long)blockIdx.x * blockDim.x + threadIdx.x) * 8;
    if (i >= n) return;
    f32x4 a = *reinterpret_cast<const f32x4*>(in + i);
    f32x4 b = *reinterpret_cast<const f32x4*>(in + i + 4);
    f16x8 h;
    h[0] = (_Float16)a[0]; h[1] = (_Float16)a[1]; h[2] = (_Float16)a[2]; h[3] = (_Float16)a[3];
    h[4] = (_Float16)b[0]; h[5] = (_Float16)b[1]; h[6] = (_Float16)b[2]; h[7] = (_Float16)b[3];
    *reinterpret_cast<f16x8*>(outp + i) = h;
}

// ---------------- gather + mean (one wave per dst node), fp16 source ----------------
__global__ void gather_mean_fp16(const _Float16* __restrict__ Xh, const int* __restrict__ rp,
                                 const int* __restrict__ ss, float* __restrict__ mean, int ndst) {
    int wave = threadIdx.x >> 6, lane = threadIdx.x & 63;
    int d = blockIdx.x * 4 + wave;
    if (d >= ndst) return;
    int beg = rp[d], end = rp[d + 1];
    int lo4 = lane * 4;
    f32x4 a0 = (f32x4)(0.f), a1 = (f32x4)(0.f), a2 = (f32x4)(0.f), a3 = (f32x4)(0.f);
    int j = beg;
    for (; j + 8 <= end; j += 8) {
        int s0 = ss[j + 0], s1 = ss[j + 1], s2 = ss[j + 2], s3 = ss[j + 3];
        int s4 = ss[j + 4], s5 = ss[j + 5], s6 = ss[j + 6], s7 = ss[j + 7];
        f16x4 h0 = *reinterpret_cast<const f16x4*>(Xh + (size_t)s0 * DD + lo4);
        f16x4 h1 = *reinterpret_cast<const f16x4*>(Xh + (size_t)s1 * DD + lo4);
        f16x4 h2 = *reinterpret_cast<const f16x4*>(Xh + (size_t)s2 * DD + lo4);
        f16x4 h3 = *reinterpret_cast<const f16x4*>(Xh + (size_t)s3 * DD + lo4);
        f16x4 h4 = *reinterpret_cast<const f16x4*>(Xh + (size_t)s4 * DD + lo4);
        f16x4 h5 = *reinterpret_cast<const f16x4*>(Xh + (size_t)s5 * DD + lo4);
        f16x4 h6 = *reinterpret_cast<const f16x4*>(Xh + (size_t)s6 * DD + lo4);
        f16x4 h7 = *reinterpret_cast<const f16x4*>(Xh + (size_t)s7 * DD + lo4);
        a0 += __builtin_convertvector(h0, f32x4);
        a1 += __builtin_convertvector(h1, f32x4);
        a2 += __builtin_convertvector(h2, f32x4);
        a3 += __builtin_convertvector(h3, f32x4);
        a0 += __builtin_convertvector(h4, f32x4);
        a1 += __builtin_convertvector(h5, f32x4);
        a2 += __builtin_convertvector(h6, f32x4);
        a3 += __builtin_convertvector(h7, f32x4);
    }
    for (; j + 4 <= end; j += 4) {
        int s0 = ss[j + 0], s1 = ss[j + 1], s2 = ss[j + 2], s3 = ss[j + 3];
        f16x4 h0 = *reinterpret_cast<const f16x4*>(Xh + (size_t)s0 * DD + lo4);
        f16x4 h1 = *reinterpret_cast<const f16x4*>(Xh + (size_t)s1 * DD + lo4);
        f16x4 h2 = *reinterpret_cast<const f16x4*>(Xh + (size_t)s2 * DD + lo4);
        f16x4 h3 = *reinterpret_cast<const f16x4*>(Xh + (size_t)s3 * DD + lo4);
        a0 += __builtin_convertvector(h0, f32x4);
        a1 += __builtin_convertvector(h1, f32x4);
        a2 += __builtin_convertvector(h2, f32x4);
        a3 += __builtin_convertvector(h3, f32x4);
    }
    for (; j < end; ++j) {
        int s = ss[j];
        f16x4 h0 = *reinterpret_cast<const f16x4*>(Xh + (size_t)s * DD + lo4);
        a0 += __builtin_convertvector(h0, f32x4);
    }
    f32x4 s = (a0 + a1) + (a2 + a3);
    int dg = end - beg;
    float inv = 1.0f / (float)(dg > 0 ? dg : 1);
    s *= inv;
    *reinterpret_cast<f32x4*>(mean + (size_t)d * DD + lo4) = s;
}

// ---------------- build 2-level fp16 split weight image (layers, pre-swizzled) -------------
__global__ void build_wimg(const float* __restrict__ Wa0, const float* __restrict__ Wb0,
                           const float* __restrict__ Wa1, const float* __restrict__ Wb1,
                           u16* __restrict__ img) {
    int blk = blockIdx.x;           // 0..63
    int layer = blk >> 5;
    int ntile = (blk >> 4) & 1;
    int chunk = blk & 15;
    const float* Wa = layer ? Wa1 : Wa0;
    const float* Wb = layer ? Wb1 : Wb0;
    int t = threadIdx.x;
    int row = t >> 1, half = t & 1;
    int n = ntile * 128 + row;
    int kg = chunk * 32 + half * 16;
    const float* W = (kg < 256) ? Wa : Wb;
    int kk = kg & 255;
    const float* src = W + (size_t)n * 256 + kk;
    float x[16];
#pragma unroll
    for (int j = 0; j < 16; j += 4) {
        float4 v = *reinterpret_cast<const float4*>(src + j);
        x[j] = v.x; x[j + 1] = v.y; x[j + 2] = v.z; x[j + 3] = v.w;
    }
    _Float16 h0[16], h1[16];
#pragma unroll
    for (int j = 0; j < 16; ++j) split2(x[j], h0[j], h1[j]);
    int rs = (row >> 1) & 3;
    int q0 = (half * 2 + 0) ^ rs;
    int q1 = (half * 2 + 1) ^ rs;
    u16* base = img + (size_t)blk * IMG_U16 + row * 32;
    *reinterpret_cast<f16x8*>(base + q0 * 8)            = pack8(h0);
    *reinterpret_cast<f16x8*>(base + q1 * 8)            = pack8(h0 + 8);
    *reinterpret_cast<f16x8*>(base + LVL2_U16 + q0 * 8) = pack8(h1);
    *reinterpret_cast<f16x8*>(base + LVL2_U16 + q1 * 8) = pack8(h1 + 8);
}

// ---------------- build head weight image: rows = [Wp(7) | Wpp(280) | zeros(97)] -----------
// 48 chunk-images (3 ntiles x 16 chunks), K = 512 direct (hcat = [h2|h1]).
__global__ void build_wimg_head(const float* __restrict__ Wp, const float* __restrict__ Wpp,
                                u16* __restrict__ img) {
    int blk = blockIdx.x;           // 0..47 = ntile*16 + chunk
    int ntile = blk >> 4;
    int chunk = blk & 15;
    int t = threadIdx.x;
    int row = t >> 1, half = t & 1;
    int r = ntile * 128 + row;      // output col 0..383
    int kg = chunk * 32 + half * 16;
    float x[16];
    const float* src = nullptr;
    if (r < CC)            src = Wp  + (size_t)r * 512 + kg;
    else if (r < CC + CC * KK) src = Wpp + (size_t)(r - CC) * 512 + kg;
    if (src) {
#pragma unroll
        for (int j = 0; j < 16; j += 4) {
            float4 v = *reinterpret_cast<const float4*>(src + j);
            x[j] = v.x; x[j + 1] = v.y; x[j + 2] = v.z; x[j + 3] = v.w;
        }
    } else {
#pragma unroll
        for (int j = 0; j < 16; ++j) x[j] = 0.f;
    }
    _Float16 h0[16], h1[16];
#pragma unroll
    for (int j = 0; j < 16; ++j) split2(x[j], h0[j], h1[j]);
    int rs = (row >> 1) & 3;
    int q0 = (half * 2 + 0) ^ rs;
    int q1 = (half * 2 + 1) ^ rs;
    u16* base = img + (size_t)blk * IMG_U16 + row * 32;
    *reinterpret_cast<f16x8*>(base + q0 * 8)            = pack8(h0);
    *reinterpret_cast<f16x8*>(base + q1 * 8)            = pack8(h0 + 8);
    *reinterpret_cast<f16x8*>(base + LVL2_U16 + q0 * 8) = pack8(h1);
    *reinterpret_cast<f16x8*>(base + LVL2_U16 + q1 * 8) = pack8(h1 + 8);
}

// ---------------- 2-level fp16 split MFMA GEMM: out = act([X0|X1] @ Wimg^T + b) ------------
// Generalized: ldo = output stride AND col bound (cols >= ldo skipped), dorelu flag,
// bias may be null, outh optional fp16 shadow (stride DD).
__global__ __launch_bounds__(256, 3) void gemm_f16(const float* __restrict__ X0,
                                                   const float* __restrict__ X1,
                                                   const u16* __restrict__ imgL,
                                                   const float* __restrict__ bias,
                                                   float* __restrict__ out,
                                                   _Float16* __restrict__ outh,
                                                   int M, int ldo, int dorelu) {
    __shared__ __align__(16) u16 Asl[2 * LVL2_U16];
    __shared__ __align__(16) u16 Bsl[2 * LVL2_U16];
    int t = threadIdx.x;
    int wave = t >> 6, lane = t & 63;
    int m0 = blockIdx.x * 128;
    int ntile = blockIdx.y;
    int wy = wave >> 1, wx = wave & 1;     // wave position: m-half, n-half

    f32x4 acc[4][4];
#pragma unroll
    for (int i = 0; i < 4; ++i)
#pragma unroll
        for (int j = 0; j < 4; ++j) acc[i][j] = (f32x4)(0.f);

    // A staging mapping: 256 thr -> 128 rows x 2 k-halves (16 f32 each)
    int arow_l = t >> 1;
    int akh = t & 1;
    int arow = m0 + arow_l; if (arow >= M) arow = M - 1;

    // fragment positions: A/B operand elem j -> k = (lane>>4)*8 + j  => quad q = lane>>4
    int fr = lane & 15;
    int q  = lane >> 4;
    int frm = wy * 64 + fr;
    int frn = wx * 64 + fr;

    const u16* imgT = imgL + (size_t)ntile * 16 * IMG_U16;

    for (int c = 0; c < 16; ++c) {
        // ---- stage B: async global->LDS, 16 segs of 1024 B (wave-uniform seg), linear copy
        const char* src = (const char*)(imgT + (size_t)c * IMG_U16);
#pragma unroll
        for (int i = 0; i < 4; ++i) {
            int seg = wave * 4 + i;
            async16(src + seg * 1024 + lane * 16, (char*)Bsl + seg * 1024 + lane * 16);
        }
        // ---- stage A: load 16 f32, split2, write 4 swizzled quads
        {
            const float* Xs = (c < 8) ? X0 : X1;
            int kc = (c & 7) * 32;
            const float* p = Xs + (size_t)arow * 256 + kc + akh * 16;
            float x[16];
#pragma unroll
            for (int j = 0; j < 16; j += 4) {
                float4 v = *reinterpret_cast<const float4*>(p + j);
                x[j] = v.x; x[j + 1] = v.y; x[j + 2] = v.z; x[j + 3] = v.w;
            }
            _Float16 h0[16], h1[16];
#pragma unroll
            for (int j = 0; j < 16; ++j) split2(x[j], h0[j], h1[j]);
            int rs = (arow_l >> 1) & 3;
            int q0 = (akh * 2 + 0) ^ rs;
            int q1 = (akh * 2 + 1) ^ rs;
            u16* d = Asl + arow_l * 32;
            *reinterpret_cast<f16x8*>(d + q0 * 8)            = pack8(h0);
            *reinterpret_cast<f16x8*>(d + q1 * 8)            = pack8(h0 + 8);
            *reinterpret_cast<f16x8*>(d + LVL2_U16 + q0 * 8) = pack8(h1);
            *reinterpret_cast<f16x8*>(d + LVL2_U16 + q1 * 8) = pack8(h1 + 8);
        }
        __syncthreads();
        // ---- fragments + MFMA (3 per subtile)
        f16x8 bf[4][2];
#pragma unroll
        for (int ns = 0; ns < 4; ++ns) {
            int r = frn + ns * 16;
            int off = r * 32 + ((q ^ ((r >> 1) & 3))) * 8;
            bf[ns][0] = *reinterpret_cast<const f16x8*>(Bsl + off);
            bf[ns][1] = *reinterpret_cast<const f16x8*>(Bsl + LVL2_U16 + off);
        }
#pragma unroll
        for (int ms = 0; ms < 4; ++ms) {
            int r = frm + ms * 16;
            int off = r * 32 + ((q ^ ((r >> 1) & 3))) * 8;
            f16x8 af0 = *reinterpret_cast<const f16x8*>(Asl + off);
            f16x8 af1 = *reinterpret_cast<const f16x8*>(Asl + LVL2_U16 + off);
#pragma unroll
            for (int ns = 0; ns < 4; ++ns) {
                f32x4 a = acc[ms][ns];
                a = __builtin_amdgcn_mfma_f32_16x16x32_f16(af0, bf[ns][0], a, 0, 0, 0);
                a = __builtin_amdgcn_mfma_f32_16x16x32_f16(af0, bf[ns][1], a, 0, 0, 0);
                a = __builtin_amdgcn_mfma_f32_16x16x32_f16(af1, bf[ns][0], a, 0, 0, 0);
                acc[ms][ns] = a;
            }
        }
        __syncthreads();
    }
    // ---- epilogue: +bias, act, store f32 (C/D: col=lane&15, row=(lane>>4)*4+reg)
#pragma unroll
    for (int ms = 0; ms < 4; ++ms) {
        int rbase = m0 + wy * 64 + ms * 16 + (lane >> 4) * 4;
#pragma unroll
        for (int ns = 0; ns < 4; ++ns) {
            int col = ntile * 128 + wx * 64 + ns * 16 + (lane & 15);
            if (col >= ldo) continue;
            float bcol = bias ? bias[col] : 0.f;
#pragma unroll
            for (int r = 0; r < 4; ++r) {
                int row = rbase + r;
                if (row < M) {
                    float v = acc[ms][ns][r] + bcol;
                    if (dorelu) v = fmaxf(v, 0.f);
                    out[(size_t)row * ldo + col] = v;
                    if (outh) outh[(size_t)row * DD + col] = (_Float16)v;
                }
            }
        }
    }
}

// ---------------- head select: argmax over 7 score cols -> copy chosen 40 ----------------
// wave per node; all lanes redundantly compute argmax (broadcast loads), lanes 0..39 copy.
__global__ void select_kernel(const float* __restrict__ all, float* __restrict__ out) {
    int wave = threadIdx.x >> 6, lane = threadIdx.x & 63;
    int n = blockIdx.x * 4 + wave;
    if (n >= NN2) return;
    const float* row = all + (size_t)n * NHEAD;
    float best = row[0]; int bc = 0;
#pragma unroll
    for (int c = 1; c < CC; ++c) {
        float s = row[c];
        if (s > best) { best = s; bc = c; }  // strict > : first-index tie-break (np.argmax)
    }
    if (lane < KK) out[(size_t)n * KK + lane] = row[CC + bc * KK + lane];
}

extern "C" void kernel_launch(void* const* d_in, const int* in_sizes, int n_in,
                              void* d_out, int out_size, void* d_ws, size_t ws_size,
                              hipStream_t stream) {
    const float* inputs  = (const float*)d_in[0];
    const float* Wself0  = (const float*)d_in[1];
    const float* Wneigh0 = (const float*)d_in[2];
    const float* b0      = (const float*)d_in[3];
    const float* Wself1  = (const float*)d_in[4];
    const float* Wneigh1 = (const float*)d_in[5];
    const float* b1      = (const float*)d_in[6];
    const float* Wp      = (const float*)d_in[7];
    const float* Wpp     = (const float*)d_in[8];
    const int* es0 = (const int*)d_in[9];
    const int* ed0 = (const int*)d_in[10];
    const int* es1 = (const int*)d_in[11];
    const int* ed1 = (const int*)d_in[12];

    char* ws = (char*)d_ws;
    size_t off = 0;
    auto alloc = [&](size_t bytes) -> void* {
        void* p = (void*)(ws + off);
        off += (bytes + 255) & ~(size_t)255;
        return p;
    };
    // zero-initialized region (one memset)
    int* cnt0 = (int*)alloc((size_t)NN1 * 4);
    int* cnt1 = (int*)alloc((size_t)NN2 * 4);
    int* cur0 = (int*)alloc((size_t)NN1 * 4);
    int* cur1 = (int*)alloc((size_t)NN2 * 4);
    int* rp0  = (int*)alloc((size_t)(NN1 + 1) * 4);
    int* rp1  = (int*)alloc((size_t)(NN2 + 1) * 4);
    int* part0 = (int*)alloc(1024);
    int* part1 = (int*)alloc(1024);
    size_t zero_bytes = off;
    // uninitialized scratch
    int*   ss0   = (int*)alloc((size_t)EE0 * 4);
    int*   ss1   = (int*)alloc((size_t)EE1 * 4);
    u16*   wimg  = (u16*)alloc((size_t)(64 + 48) * IMG_U16 * 2); // layer(64) + head(48) images
    u16*   wimgH = wimg + (size_t)64 * IMG_U16;
    // xh (fp16 inputs, 102.4MB) aliases h1 (f32, 102.4MB): xh is dead before
    // gemm0 writes h1 (serial stream: to_fp16 -> gather0 reads xh -> gemm0 writes h1).
    _Float16* xh = (_Float16*)alloc((size_t)NN0 * DD * 2);
    float*    h1 = (float*)xh;
    _Float16* h1h  = (_Float16*)alloc((size_t)NN1 * DD * 2);  // fp16 shadow of h1 for gather1
    float* mean0 = (float*)alloc((size_t)NN1 * DD * 4);
    float* mean1 = mean0;                      // mean0 dead after gemm0; reuse
    float* h2    = mean0 + (size_t)NN2 * DD;   // second half of the same region
    float* allout = (float*)alloc((size_t)NN2 * NHEAD * 4);   // 57.6 MB head output

    hipMemsetAsync(d_ws, 0, zero_bytes, stream);

    // CSR build, layer 0 and 1
    hist_kernel<<<(EE0 + 255) / 256, 256, 0, stream>>>(ed0, cnt0, EE0);
    hist_kernel<<<(EE1 + 255) / 256, 256, 0, stream>>>(ed1, cnt1, EE1);
    int nb0 = (NN1 + 1023) / 1024, nb1 = (NN2 + 1023) / 1024;
    scan_block_kernel<<<nb0, 256, 0, stream>>>(cnt0, rp0 + 1, part0, NN1);
    scan_partials_kernel<<<1, 256, 0, stream>>>(part0, nb0);
    scan_add_kernel<<<nb0, 256, 0, stream>>>(rp0 + 1, part0, NN1);
    scan_block_kernel<<<nb1, 256, 0, stream>>>(cnt1, rp1 + 1, part1, NN2);
    scan_partials_kernel<<<1, 256, 0, stream>>>(part1, nb1);
    scan_add_kernel<<<nb1, 256, 0, stream>>>(rp1 + 1, part1, NN2);
    fill_kernel<<<(EE0 + 255) / 256, 256, 0, stream>>>(es0, ed0, rp0, cur0, ss0, EE0);
    fill_kernel<<<(EE1 + 255) / 256, 256, 0, stream>>>(es1, ed1, rp1, cur1, ss1, EE1);

    // split weights into pre-swizzled fp16 images (layers + head)
    build_wimg<<<64, 256, 0, stream>>>(Wself0, Wneigh0, Wself1, Wneigh1, wimg);
    build_wimg_head<<<48, 256, 0, stream>>>(Wp, Wpp, wimgH);

    // fp16 copy of inputs for the gather (halves random-gather miss bytes)
    long nx = (long)NN0 * DD;
    to_fp16<<<(int)(nx / 8 / 256), 256, 0, stream>>>(inputs, xh, nx);

    // layer 0: mean aggregate (fp16 gather) + split-fp16 MFMA GEMM (relu, + fp16 shadow h1h)
    gather_mean_fp16<<<(NN1 + 3) / 4, 256, 0, stream>>>(xh, rp0, ss0, mean0, NN1);
    dim3 g0((NN1 + 127) / 128, 2);
    gemm_f16<<<g0, 256, 0, stream>>>(inputs, mean0, wimg, b0, h1, h1h, NN1, DD, 1);

    // layer 1 (gather reads fp16 shadow)
    gather_mean_fp16<<<(NN2 + 3) / 4, 256, 0, stream>>>(h1h, rp1, ss1, mean1, NN2);
    dim3 g1((NN2 + 127) / 128, 2);
    gemm_f16<<<g1, 256, 0, stream>>>(h1, mean1, wimg + (size_t)32 * IMG_U16, b1, h2, nullptr, NN2, DD, 1);

    // head as GEMM: all 287 outputs (7 scores + 280 projections) via MFMA, then select
    dim3 gh((NN2 + 127) / 128, 3);
    gemm_f16<<<gh, 256, 0, stream>>>(h2, h1, wimgH, nullptr, allout, nullptr, NN2, NHEAD, 0);
    select_kernel<<<(NN2 + 3) / 4, 256, 0, stream>>>(allout, (float*)d_out);
}